// Round 2
// baseline (9.752 us; speedup 1.0000x reference)
//
#include <hip/hip_runtime.h>
#include <hip/hip_bf16.h>

// LengthRegulator: d = round(dur) * (1 - pad); cumsum over tokens; output
// mel2token[b][p] = 1-based token index whose [cum_prev, cum) span contains p,
// 0 for p >= row total. Output int32, shape (B, T_mel), T_mel = out_size/B.
//
// Latency-regime design: one block per batch row; wave-shuffle inclusive scan
// (6 shfl steps + single 8-entry wave-total exchange, 1 barrier total), then
// each thread SCATTERS its token index across its duration span (<= DUR_MAX=8
// stores) instead of binary-searching per output position. Tail zero-filled
// cooperatively (harness poisons d_out, so every element must be written).

#define T_TXT 512
#define BATCH 32
#define NWAVES (T_TXT / 64)

__global__ __launch_bounds__(T_TXT) void LengthRegulator_8169027797081_kernel(
    const float* __restrict__ dur, const int* __restrict__ pad,
    int* __restrict__ out, int T_mel) {
    const int b = blockIdx.x;
    const int t = threadIdx.x;
    const int lane = t & 63;
    const int w = t >> 6;

    // load + round + mask padding
    int d = (int)rintf(dur[b * T_TXT + t]);
    d *= (1 - pad[b * T_TXT + t]);

    // per-wave inclusive scan (registers only)
    int x = d;
    #pragma unroll
    for (int off = 1; off < 64; off <<= 1) {
        int y = __shfl_up(x, off, 64);
        if (lane >= off) x += y;
    }

    // exchange wave totals
    __shared__ int wsum[NWAVES];
    if (lane == 63) wsum[w] = x;
    __syncthreads();

    int base = 0, total = 0;
    #pragma unroll
    for (int i = 0; i < NWAVES; ++i) {
        int s = wsum[i];
        if (i < w) base += s;
        total += s;
    }

    const int cum = base + x;
    const int cum_prev = cum - d;
    int* __restrict__ row = out + b * T_mel;

    // scatter token index over its span (d <= 8)
    for (int p = cum_prev; p < cum; ++p) row[p] = t + 1;

    // zero the tail [total, T_mel)
    for (int p = total + t; p < T_mel; p += T_TXT) row[p] = 0;
}

extern "C" void kernel_launch(void* const* d_in, const int* in_sizes, int n_in,
                              void* d_out, int out_size, void* d_ws, size_t ws_size,
                              hipStream_t stream) {
    const float* dur = (const float*)d_in[0];
    const int* pad = (const int*)d_in[1];
    int* out = (int*)d_out;
    const int T_mel = out_size / BATCH;
    LengthRegulator_8169027797081_kernel<<<BATCH, T_TXT, 0, stream>>>(dur, pad, out, T_mel);
}